// Round 1
// baseline (86.125 us; speedup 1.0000x reference)
//
#include <hip/hip_runtime.h>

// Problem constants (B=16, H=512, W=512, C=3)
#define BDIM 16
#define HDIM 512
#define WDIM 512
#define CDIM 3

typedef float f32x2 __attribute__((ext_vector_type(2)));
typedef float f32x4 __attribute__((ext_vector_type(4)));

// Packed low-alignment vector types (frame pixel stride = 12 B).
struct __attribute__((aligned(4))) pf4 { float x, y, z, w; };
struct __attribute__((aligned(4))) pf2 { float x, y; };

struct Taps {
    pf4 a0; pf2 b0;   // row0: tl0 tl1 tl2 tr0 | tr1 tr2
    pf4 a1; pf2 b1;   // row1: bl0 bl1 bl2 br0 | br1 br2
    float ax, ay;
};

__device__ __forceinline__ Taps bilinear_load(
    const float* __restrict__ img, float qy, float qx)
{
    float fy = fminf(fmaxf(floorf(qy), 0.0f), (float)(HDIM - 2));
    float fx = fminf(fmaxf(floorf(qx), 0.0f), (float)(WDIM - 2));
    Taps tp;
    tp.ay = fminf(fmaxf(qy - fy, 0.0f), 1.0f);
    tp.ax = fminf(fmaxf(qx - fx, 0.0f), 1.0f);
    int iy = (int)fy;
    int ix = (int)fx;
    const float* r0 = img + ((size_t)iy * WDIM + ix) * CDIM;
    const float* r1 = r0 + WDIM * CDIM;
    tp.a0 = *reinterpret_cast<const pf4*>(r0);
    tp.b0 = *reinterpret_cast<const pf2*>(r0 + 4);
    tp.a1 = *reinterpret_cast<const pf4*>(r1);
    tp.b1 = *reinterpret_cast<const pf2*>(r1 + 4);
    return tp;
}

__device__ __forceinline__ void bilinear_eval(const Taps& t, float g[3])
{
    float tl[3] = {t.a0.x, t.a0.y, t.a0.z};
    float tr[3] = {t.a0.w, t.b0.x, t.b0.y};
    float bl[3] = {t.a1.x, t.a1.y, t.a1.z};
    float br[3] = {t.a1.w, t.b1.x, t.b1.y};
#pragma unroll
    for (int c = 0; c < CDIM; ++c) {
        float top = tl[c] + t.ax * (tr[c] - tl[c]);
        float bot = bl[c] + t.ax * (br[c] - bl[c]);
        g[c] = top + t.ay * (bot - top);
    }
}

// R15: adjacent-pixel pairing. Each thread handles px (2i, 2i+1) of ONE
// row; each block = one full row of one batch. Gains vs dual-chain:
//  - flow loads:   4x dwordx2  -> 2x dwordx4 (16-aligned)
//  - vis loads:    4x dword    -> 2x dwordx2 (8-aligned)
//  - tind:         2x vector ld-> 1x uniform s_load (b is blockIdx-derived)
//  - stores:       6x strided dword -> 3x dense dwordx2, nontemporal so the
//    50 MB write stream does not evict the 201 MB input set from the 256 MB
//    LLC (251 MB ~= capacity was the thrash boundary).
// Kept: 8192x256 launch (4 residency rounds), XCD-chunked bijective swizzle
// (consecutive same-XCD blocks = adjacent rows -> ~320 KB tap window hot in
// the 4 MB XCD L2), 16-tap-load pin via sched_barrier, rcpf.
__global__ __launch_bounds__(256) void warp_interp_kernel(
    const float* __restrict__ frames0,  // [B,H,W,3]
    const float* __restrict__ flow0,    // [B,H,W,2]
    const float* __restrict__ vis0,     // [B,H,W,1]
    const float* __restrict__ frames1,  // [B,H,W,3]
    const float* __restrict__ flow1,    // [B,H,W,2]
    const float* __restrict__ vis1,     // [B,H,W,1]
    const float* __restrict__ tind,     // [B]
    float* __restrict__ out)            // [B,H,W,3]
{
    const int bid = blockIdx.x;
    const int row = (bid & 7) * 1024 + (bid >> 3);  // bijective: 8192 = 8*1024
    const int y   = row & (HDIM - 1);
    const int b   = row >> 9;                       // uniform per block
    const int x0  = (int)threadIdx.x * 2;
    const int x1  = x0 + 1;
    const size_t P = (size_t)row * WDIM + (size_t)x0;  // even pixel index

    // Phase 1: stream loads, vectorized over the adjacent pair.
    // byte offsets: flow 16*(row*256+tid) -> 16-aligned; vis 8*(...) -> 8-al.
    f32x4 f0 = *reinterpret_cast<const f32x4*>(flow0 + 2 * P);  // fyA fxA fyB fxB
    f32x4 f1 = *reinterpret_cast<const f32x4*>(flow1 + 2 * P);
    f32x2 v0 = *reinterpret_cast<const f32x2*>(vis0 + P);
    f32x2 v1 = *reinterpret_cast<const f32x2*>(vis1 + P);
    const float t = tind[b];                         // uniform -> s_load

    const float* img0 = frames0 + (size_t)b * (HDIM * WDIM * CDIM);
    const float* img1 = frames1 + (size_t)b * (HDIM * WDIM * CDIM);

    // Phase 2: issue all 16 tap loads (4 groups x 4 loads)
    Taps t0A = bilinear_load(img0, (float)y - f0.x, (float)x0 - f0.y);
    Taps t1A = bilinear_load(img1, (float)y - f1.x, (float)x0 - f1.y);
    Taps t0B = bilinear_load(img0, (float)y - f0.z, (float)x1 - f0.w);
    Taps t1B = bilinear_load(img1, (float)y - f1.z, (float)x1 - f1.w);

    // Pin: no eval may be hoisted above / no load sunk below this point.
    __builtin_amdgcn_sched_barrier(0);

    // Phase 3: eval + dense 24 B/thread nontemporal store
    float w0A = (1.0f - t) * v0.x, w1A = t * v1.x;
    float invA = __builtin_amdgcn_rcpf(w0A + w1A + 1e-12f);
    float w0B = (1.0f - t) * v0.y, w1B = t * v1.y;
    float invB = __builtin_amdgcn_rcpf(w0B + w1B + 1e-12f);

    float g0[3], g1[3], o[6];
    bilinear_eval(t0A, g0);
    bilinear_eval(t1A, g1);
    o[0] = (w0A * g0[0] + w1A * g1[0]) * invA;
    o[1] = (w0A * g0[1] + w1A * g1[1]) * invA;
    o[2] = (w0A * g0[2] + w1A * g1[2]) * invA;
    bilinear_eval(t0B, g0);
    bilinear_eval(t1B, g1);
    o[3] = (w0B * g0[0] + w1B * g1[0]) * invB;
    o[4] = (w0B * g0[1] + w1B * g1[1]) * invB;
    o[5] = (w0B * g0[2] + w1B * g1[2]) * invB;

    float* op = out + 3 * P;  // byte offset 24*(row*256+tid) -> 8-aligned
    f32x2 s0; s0.x = o[0]; s0.y = o[1];
    f32x2 s1; s1.x = o[2]; s1.y = o[3];
    f32x2 s2; s2.x = o[4]; s2.y = o[5];
    __builtin_nontemporal_store(s0, reinterpret_cast<f32x2*>(op));
    __builtin_nontemporal_store(s1, reinterpret_cast<f32x2*>(op + 2));
    __builtin_nontemporal_store(s2, reinterpret_cast<f32x2*>(op + 4));
}

extern "C" void kernel_launch(void* const* d_in, const int* in_sizes, int n_in,
                              void* d_out, int out_size, void* d_ws, size_t ws_size,
                              hipStream_t stream) {
    const float* frames0 = (const float*)d_in[0];
    const float* flow0   = (const float*)d_in[1];
    const float* vis0    = (const float*)d_in[2];
    const float* frames1 = (const float*)d_in[3];
    const float* flow1   = (const float*)d_in[4];
    const float* vis1    = (const float*)d_in[5];
    const float* tind    = (const float*)d_in[6];
    float* out = (float*)d_out;

    const int block = 256;
    const int grid = 8192;  // one row per block, 4 residency rounds

    warp_interp_kernel<<<grid, block, 0, stream>>>(
        frames0, flow0, vis0, frames1, flow1, vis1, tind, out);
}